// Round 5
// baseline (811.817 us; speedup 1.0000x reference)
//
#include <hip/hip_runtime.h>
#include <math.h>

#define HID 128
#define LSEQ 1024
#define NB 64  // batch
#define CH_PER_DIR 8192  // NB * HID
#define SUB 32           // subchunk length for chunk-parallel scan
#define NQG (LSEQ / SUB) // 32 global subchunks per direction

typedef __attribute__((ext_vector_type(4))) float f32x4;
typedef __attribute__((ext_vector_type(8))) short bf16x8;
typedef __attribute__((ext_vector_type(8))) unsigned short u16x8;
typedef __attribute__((ext_vector_type(4))) unsigned short u16x4;

__device__ __forceinline__ unsigned short f2bf(float x) {
    union { float f; unsigned int u; } a; a.f = x;
    unsigned int r = a.u + 0x7FFFu + ((a.u >> 16) & 1u);
    return (unsigned short)(r >> 16);
}
__device__ __forceinline__ float bf2f(unsigned short h) {
    union { float f; unsigned int u; } a; a.u = ((unsigned int)h) << 16;
    return a.f;
}
__device__ __forceinline__ float sigmoidf_(float x) { return 1.0f / (1.0f + __expf(-x)); }
__device__ __forceinline__ float seluf_(float x) {
    const float sc = 1.0507009873554805f, al = 1.6732632423543772f;
    return x > 0.0f ? sc * x : sc * al * (__expf(x) - 1.0f);
}

__device__ __forceinline__ void gload16(const unsigned short* g, unsigned short* l) {
    __builtin_amdgcn_global_load_lds(
        (const __attribute__((address_space(1))) unsigned int*)g,
        (__attribute__((address_space(3))) unsigned int*)l, 16, 0, 0);
}

// W (K x N fp32, N = 2H*kw) -> Wt plane-major: row n' = dir*128*kw + j*128 + h, bf16 [n'][k]
__global__ __launch_bounds__(256) void conv_wt(const float* __restrict__ W,
                                               unsigned short* __restrict__ Wt,
                                               int K, int N, int kw) {
    int idx = blockIdx.x * 256 + threadIdx.x;
    if (idx >= K * N) return;
    int k = idx / N, n = idx - k * N;
    const int dir = n / (128 * kw);
    const int rem = n - dir * 128 * kw;
    const int h = rem / kw, j = rem - h * kw;
    const int np = dir * 128 * kw + j * 128 + h;
    Wt[(size_t)np * K + k] = f2bf(W[idx]);
}

// fp32 -> bf16 flat convert
__global__ __launch_bounds__(256) void conv_in(const float* __restrict__ in,
                                               unsigned short* __restrict__ outp,
                                               int n4) {
    int idx = blockIdx.x * 256 + threadIdx.x;
    if (idx >= n4) return;
    const float4 v = *reinterpret_cast<const float4*>(in + (size_t)idx * 4);
    u16x4 w;
    w[0] = f2bf(v.x); w[1] = f2bf(v.y); w[2] = f2bf(v.z); w[3] = f2bf(v.w);
    *(u16x4*)(outp + (size_t)idx * 4) = w;
}

// C[M x NC] = A[M x K] * Bt[NC x K]^T, bf16 in / fp32 acc / bf16 out.
// 128x128 tile, BK=64, 4 waves. global_load_lds staging w/ swizzled source,
// XCD-friendly 1D grid: bid = mg*(NN*8) + n*8 + mi.
template <int K, int NC>
__global__ __launch_bounds__(256) void gemm_v2(const unsigned short* __restrict__ A,
                                               const unsigned short* __restrict__ Bt,
                                               unsigned short* __restrict__ C) {
    constexpr int NN = NC / 128;
    __shared__ __align__(16) unsigned short sm[2][128 * 64];

    const int bid = blockIdx.x;
    const int mi = bid & 7;
    const int tt = bid >> 3;
    const int n = tt % NN;
    const int mg = tt / NN;
    const int m0 = (mg * 8 + mi) * 128;
    const int n0 = n * 128;

    const int tid = threadIdx.x;
    const int r = tid >> 3, c8 = tid & 7;
    const int swz = (c8 * 8) ^ ((r & 7) * 8);

    const int lane = tid & 63;
    const int wid = tid >> 6;
    const int wr = wid >> 1, wc = wid & 1;
    const int rlo = lane & 15, g = lane >> 4;

    f32x4 acc[4][4] = {};

    const unsigned short* gA = A + (size_t)m0 * K + swz;
    const unsigned short* gB = Bt + (size_t)n0 * K + swz;

#pragma unroll
    for (int k0 = 0; k0 < K; k0 += 64) {
#pragma unroll
        for (int i = 0; i < 4; ++i) {
            gload16(gA + (size_t)(r + 32 * i) * K + k0, &sm[0][i * 2048 + tid * 8]);
            gload16(gB + (size_t)(r + 32 * i) * K + k0, &sm[1][i * 2048 + tid * 8]);
        }
        __syncthreads();

        bf16x8 af[2][4], bff[2][4];
#pragma unroll
        for (int kk = 0; kk < 2; ++kk) {
            const int ke = kk * 32 + g * 8;
#pragma unroll
            for (int m = 0; m < 4; ++m) {
                const int row = wr * 64 + m * 16 + rlo;
                af[kk][m] = *(const bf16x8*)(&sm[0][row * 64 + (ke ^ ((row & 7) * 8))]);
            }
#pragma unroll
            for (int nn2 = 0; nn2 < 4; ++nn2) {
                const int row = wc * 64 + nn2 * 16 + rlo;
                bff[kk][nn2] = *(const bf16x8*)(&sm[1][row * 64 + (ke ^ ((row & 7) * 8))]);
            }
        }
#pragma unroll
        for (int kk = 0; kk < 2; ++kk)
#pragma unroll
            for (int m = 0; m < 4; ++m)
#pragma unroll
                for (int nn2 = 0; nn2 < 4; ++nn2)
                    acc[m][nn2] = __builtin_amdgcn_mfma_f32_16x16x32_bf16(
                        af[kk][m], bff[kk][nn2], acc[m][nn2], 0, 0, 0);
        __syncthreads();
    }

    // epilogue via LDS: acc -> swizzled bf16 tile -> 16B coalesced stores
    unsigned short* ep = &sm[0][0];
#pragma unroll
    for (int m = 0; m < 4; ++m)
#pragma unroll
        for (int nn2 = 0; nn2 < 4; ++nn2) {
            const int col = wc * 64 + nn2 * 16 + rlo;
#pragma unroll
            for (int j = 0; j < 4; ++j) {
                const int row = wr * 64 + m * 16 + g * 4 + j;
                const int chunk = (col >> 3) ^ (row & 15);
                ep[row * 128 + chunk * 8 + (col & 7)] = f2bf(acc[m][nn2][j]);
            }
        }
    __syncthreads();
    {
        const int rr = tid >> 1;
        const int cb = (tid & 1) * 8;
#pragma unroll
        for (int k2 = 0; k2 < 8; ++k2) {
            const int c = cb + k2;
            const int pc = c ^ (rr & 15);
            const u16x8 v = *(const u16x8*)(&ep[rr * 128 + pc * 8]);
            *(u16x8*)(&C[(size_t)(m0 + rr) * NC + n0 + c * 8]) = v;
        }
    }
}

// ---- chunk-parallel SRU scan, plane-major U ----
// U row m = t*NB+b (local t in chunk); planes: u0 @ [m*NC+h], u1 @ +128, u2 @ +256, xp @ +384.

// Phase A: per (ch, subchunk q): a = prod f, b = c scanned from 0.
template <int NC>
__global__ __launch_bounds__(256) void scanA(const unsigned short* __restrict__ U,
                                             const float* __restrict__ bias,
                                             float* __restrict__ aArr,
                                             float* __restrict__ bArr,
                                             int dir, int T) {
    const int gid = blockIdx.x * 256 + threadIdx.x;
    const int ch = gid & (CH_PER_DIR - 1);
    const int q = gid >> 13;
    const int b = ch >> 7, h = ch & 127;
    const float bfb = bias[dir * HID + h];

    float aa = 1.0f, cc = 0.0f;
#pragma unroll 4
    for (int i = 0; i < SUB; ++i) {
        const int s = q * SUB + i;
        const int t = dir ? (T - 1 - s) : s;
        const size_t m = (size_t)t * NB + b;
        const float u0 = bf2f(U[m * NC + h]);
        const float u1 = bf2f(U[m * NC + 128 + h]);
        const float f = sigmoidf_(u1 + bfb);
        cc = f * cc + (1.0f - f) * u0;
        aa *= f;
    }
    aArr[(size_t)q * CH_PER_DIR + ch] = aa;
    bArr[(size_t)q * CH_PER_DIR + ch] = cc;
}

// Phase B: per channel, exclusive scan over Q subchunk summaries (carry across chunks).
__global__ __launch_bounds__(256) void scanB(const float* __restrict__ aArr,
                                             const float* __restrict__ bArr,
                                             float* __restrict__ cin,
                                             float* __restrict__ carry,
                                             int Q, int init) {
    const int ch = blockIdx.x * 256 + threadIdx.x;
    float c = init ? 0.0f : carry[ch];
    for (int q = 0; q < Q; ++q) {
        cin[(size_t)q * CH_PER_DIR + ch] = c;
        c = aArr[(size_t)q * CH_PER_DIR + ch] * c + bArr[(size_t)q * CH_PER_DIR + ch];
    }
    carry[ch] = c;
}

// Phase C: redo scan from exact cin, emit h (and/or time-partial sums for the pool).
template <int NC, bool XP_FROM_U, bool ACC>
__global__ __launch_bounds__(256) void scanC(const unsigned short* __restrict__ U,
                                             const unsigned short* __restrict__ Xprev,
                                             const float* __restrict__ bias,
                                             const float* __restrict__ cin,
                                             unsigned short* __restrict__ Xout,
                                             float* __restrict__ part,
                                             int dir, int T, int t0, int qg0) {
    const int gid = blockIdx.x * 256 + threadIdx.x;
    const int ch = gid & (CH_PER_DIR - 1);
    const int q = gid >> 13;
    const int b = ch >> 7, h = ch & 127;
    const float bfb = bias[dir * HID + h];
    const float brb = bias[2 * HID + dir * HID + h];

    float c = cin[(size_t)q * CH_PER_DIR + ch];
    float psum = 0.0f;
#pragma unroll 4
    for (int i = 0; i < SUB; ++i) {
        const int s = q * SUB + i;
        const int t = dir ? (T - 1 - s) : s;
        const size_t m = (size_t)t * NB + b;
        const size_t xrow = ((size_t)(t0 + t) * NB + b) * (2 * HID) + dir * HID + h;
        const float u0 = bf2f(U[m * NC + h]);
        const float u1 = bf2f(U[m * NC + 128 + h]);
        const float u2 = bf2f(U[m * NC + 256 + h]);
        float xp;
        if constexpr (XP_FROM_U) xp = bf2f(U[m * NC + 384 + h]);
        else                     xp = bf2f(Xprev[xrow]);
        const float f = sigmoidf_(u1 + bfb);
        const float r = sigmoidf_(u2 + brb);
        c = f * c + (1.0f - f) * u0;
        const float ho = r * seluf_(c) + (1.0f - r) * xp;
        if constexpr (ACC) psum += ho;
        else               Xout[xrow] = f2bf(ho);
    }
    if constexpr (ACC)
        part[(size_t)(qg0 + q) * (NB * 2 * HID) + b * (2 * HID) + dir * HID + h] = psum;
}

// feats = (sum over qg partials)/L; layernorm over 256.
__global__ __launch_bounds__(256) void pool2(const float* __restrict__ part,
                                             const float* __restrict__ gamma,
                                             const float* __restrict__ beta,
                                             float* __restrict__ out) {
    const int b = blockIdx.x, chn = threadIdx.x;
    float s = 0.0f;
#pragma unroll
    for (int i = 0; i < NQG; ++i) s += part[(size_t)i * (NB * 256) + b * 256 + chn];
    const float feat = s * (1.0f / LSEQ);
    __shared__ float red[256];
    red[chn] = feat; __syncthreads();
    for (int off = 128; off > 0; off >>= 1) { if (chn < off) red[chn] += red[chn + off]; __syncthreads(); }
    const float mu = red[0] * (1.0f / 256.0f);
    __syncthreads();
    const float d = feat - mu;
    red[chn] = d * d; __syncthreads();
    for (int off = 128; off > 0; off >>= 1) { if (chn < off) red[chn] += red[chn + off]; __syncthreads(); }
    const float var = red[0] * (1.0f / 256.0f);
    out[b * 256 + chn] = d * rsqrtf(var + 1e-5f) * gamma[chn] + beta[chn];
}

extern "C" void kernel_launch(void* const* d_in, const int* in_sizes, int n_in,
                              void* d_out, int out_size, void* d_ws, size_t ws_size,
                              hipStream_t stream) {
    const float* input = (const float*)d_in[0];
    const float* gamma = (const float*)d_in[3];
    const float* beta  = (const float*)d_in[4];
    const float* Wl[4] = { (const float*)d_in[1], (const float*)d_in[5],
                           (const float*)d_in[7], (const float*)d_in[9] };
    const float* bl[4] = { (const float*)d_in[2], (const float*)d_in[6],
                           (const float*)d_in[8], (const float*)d_in[10] };
    float* out = (float*)d_out;

    char* base = (char*)d_ws;
    size_t off = 0;
    auto alloc = [&](size_t bytes) { size_t o = off; off = (off + bytes + 255) & ~(size_t)255; return o; };

    unsigned short* Wt[4];
    Wt[0] = (unsigned short*)(base + alloc((size_t)1024 * 128 * 2));
    for (int i = 1; i < 4; ++i) Wt[i] = (unsigned short*)(base + alloc((size_t)768 * 256 * 2));
    unsigned short* Xa = (unsigned short*)(base + alloc((size_t)LSEQ * NB * 256 * 2));
    unsigned short* Xb = (unsigned short*)(base + alloc((size_t)LSEQ * NB * 256 * 2));
    unsigned short* Xc = (unsigned short*)(base + alloc((size_t)LSEQ * NB * 128 * 2));  // input bf16
    float* carry = (float*)(base + alloc((size_t)2 * CH_PER_DIR * 4));
    float* aArr  = (float*)(base + alloc((size_t)32 * CH_PER_DIR * 4));
    float* bArr  = (float*)(base + alloc((size_t)32 * CH_PER_DIR * 4));
    float* cinArr= (float*)(base + alloc((size_t)32 * CH_PER_DIR * 4));
    float* part  = (float*)(base + alloc((size_t)NQG * NB * 256 * 4));  // 2 MB
    if (ws_size < off + (1u << 21)) return;
    const size_t uavail = ws_size - off;
    unsigned short* U = (unsigned short*)(base + off);

    // cap T at 512 so the U chunk (<=32 MB) stays L3/L2-resident between GEMM and scans
    int T = 0;
    for (int t = 512; t >= SUB; t >>= 1)
        if ((size_t)t * 65536 <= uavail) { T = t; break; }
    if (T == 0) return;
    const int C = LSEQ / T;
    const int Q = T / SUB;
    const int nm = T * NB / 128;

    conv_in<<<(LSEQ * NB * 128 / 4 + 255) / 256, 256, 0, stream>>>(input, Xc, LSEQ * NB * 128 / 4);
    conv_wt<<<(128 * 1024 + 255) / 256, 256, 0, stream>>>(Wl[0], Wt[0], 128, 1024, 4);
    for (int i = 1; i < 4; ++i)
        conv_wt<<<(256 * 768 + 255) / 256, 256, 0, stream>>>(Wl[i], Wt[i], 256, 768, 3);

    const unsigned short* Xin[4] = { Xc, Xa, Xb, Xa };
    unsigned short* Xout[4] = { Xa, Xb, Xa, nullptr };  // layer 3 folds into pool partials

    const dim3 sgrid(CH_PER_DIR * Q / 256);

    for (int layer = 0; layer < 4; ++layer) {
        const int kw = (layer == 0) ? 4 : 3;
        const int K = (layer == 0) ? 128 : 256;
        const int Nc = HID * kw;  // 512 or 384 (per-dir plane-major columns)
        for (int dir = 0; dir < 2; ++dir) {
            const unsigned short* Bts = Wt[layer] + (size_t)dir * Nc * K;
            float* cr = carry + dir * CH_PER_DIR;
            for (int cc = 0; cc < C; ++cc) {
                const int ci = dir ? (C - 1 - cc) : cc;
                const unsigned short* Ap = Xin[layer] + (size_t)ci * T * NB * K;
                if (layer == 0)
                    gemm_v2<128, 512><<<dim3(nm * 4), 256, 0, stream>>>(Ap, Bts, U);
                else
                    gemm_v2<256, 384><<<dim3(nm * 3), 256, 0, stream>>>(Ap, Bts, U);
                if (kw == 4) scanA<512><<<sgrid, 256, 0, stream>>>(U, bl[layer], aArr, bArr, dir, T);
                else         scanA<384><<<sgrid, 256, 0, stream>>>(U, bl[layer], aArr, bArr, dir, T);
                scanB<<<CH_PER_DIR / 256, 256, 0, stream>>>(aArr, bArr, cinArr, cr, Q, cc == 0 ? 1 : 0);
                if (layer == 0)
                    scanC<512, true, false><<<sgrid, 256, 0, stream>>>(
                        U, nullptr, bl[layer], cinArr, Xout[layer], nullptr, dir, T, ci * T, ci * Q);
                else if (layer < 3)
                    scanC<384, false, false><<<sgrid, 256, 0, stream>>>(
                        U, Xin[layer], bl[layer], cinArr, Xout[layer], nullptr, dir, T, ci * T, ci * Q);
                else
                    scanC<384, false, true><<<sgrid, 256, 0, stream>>>(
                        U, Xin[layer], bl[layer], cinArr, nullptr, part, dir, T, ci * T, ci * Q);
            }
        }
    }
    pool2<<<NB, 256, 0, stream>>>(part, gamma, beta, out);
}

// Round 6
// 519.464 us; speedup vs baseline: 1.5628x; 1.5628x over previous
//
#include <hip/hip_runtime.h>
#include <math.h>

#define HID 128
#define LSEQ 1024
#define NB 64  // batch
#define SUB 32           // subchunk length for chunk-parallel scan
#define NQG (LSEQ / SUB) // 32 time-subchunks per direction
#define NCH 16384        // total channels (2 dirs * 64 b * 128 h)

typedef __attribute__((ext_vector_type(4))) float f32x4;
typedef __attribute__((ext_vector_type(8))) short bf16x8;
typedef __attribute__((ext_vector_type(8))) unsigned short u16x8;
typedef __attribute__((ext_vector_type(4))) unsigned short u16x4;

__device__ __forceinline__ unsigned short f2bf(float x) {
    union { float f; unsigned int u; } a; a.f = x;
    unsigned int r = a.u + 0x7FFFu + ((a.u >> 16) & 1u);
    return (unsigned short)(r >> 16);
}
__device__ __forceinline__ float bf2f(unsigned short h) {
    union { float f; unsigned int u; } a; a.u = ((unsigned int)h) << 16;
    return a.f;
}
__device__ __forceinline__ float sigmoidf_(float x) { return 1.0f / (1.0f + __expf(-x)); }
__device__ __forceinline__ float seluf_(float x) {
    const float sc = 1.0507009873554805f, al = 1.6732632423543772f;
    return x > 0.0f ? sc * x : sc * al * (__expf(x) - 1.0f);
}

__device__ __forceinline__ void gload16(const unsigned short* g, unsigned short* l) {
    __builtin_amdgcn_global_load_lds(
        (const __attribute__((address_space(1))) unsigned int*)g,
        (__attribute__((address_space(3))) unsigned int*)l, 16, 0, 0);
}

// W (K x N fp32, N = 2*128*kw) -> Wt plane-major: row n' = dir*128*kw + j*128 + h
__global__ __launch_bounds__(256) void conv_wt(const float* __restrict__ W,
                                               unsigned short* __restrict__ Wt,
                                               int K, int N, int kw) {
    int idx = blockIdx.x * 256 + threadIdx.x;
    if (idx >= K * N) return;
    int k = idx / N, n = idx - k * N;
    const int dir = n / (128 * kw);
    const int rem = n - dir * 128 * kw;
    const int h = rem / kw, j = rem - h * kw;
    const int np = dir * 128 * kw + j * 128 + h;
    Wt[(size_t)np * K + k] = f2bf(W[idx]);
}

__global__ __launch_bounds__(256) void conv_in(const float* __restrict__ in,
                                               unsigned short* __restrict__ outp,
                                               int n4) {
    int idx = blockIdx.x * 256 + threadIdx.x;
    if (idx >= n4) return;
    const float4 v = *reinterpret_cast<const float4*>(in + (size_t)idx * 4);
    u16x4 w;
    w[0] = f2bf(v.x); w[1] = f2bf(v.y); w[2] = f2bf(v.z); w[3] = f2bf(v.w);
    *(u16x4*)(outp + (size_t)idx * 4) = w;
}

// C[M x NC] = A[M x K] * Bt[NC x K]^T, bf16/fp32-acc/bf16. 128x128 tile, BK=64,
// 4 waves, DOUBLE-BUFFERED 2-phase: stage(t+1) overlaps compute(t), 1 barrier/iter.
// XCD-friendly 1D grid: bid = mg*(NN*8) + n*8 + mi.
template <int K, int NC>
__global__ __launch_bounds__(256) void gemm_v3(const unsigned short* __restrict__ A,
                                               const unsigned short* __restrict__ Bt,
                                               unsigned short* __restrict__ C) {
    constexpr int NN = NC / 128;
    constexpr int NT = K / 64;
    __shared__ __align__(16) unsigned short smA[2][128 * 64];
    __shared__ __align__(16) unsigned short smB[2][128 * 64];

    const int bid = blockIdx.x;
    const int mi = bid & 7;
    const int tt = bid >> 3;
    const int n = tt % NN;
    const int mg = tt / NN;
    const int m0 = (mg * 8 + mi) * 128;
    const int n0 = n * 128;

    const int tid = threadIdx.x;
    const int r = tid >> 3, c8 = tid & 7;
    const int swz = (c8 * 8) ^ ((r & 7) * 8);  // involution: applied to src AND read

    const int lane = tid & 63;
    const int wid = tid >> 6;
    const int wr = wid >> 1, wc = wid & 1;
    const int rlo = lane & 15, g = lane >> 4;

    f32x4 acc[4][4] = {};

    const unsigned short* gA = A + (size_t)m0 * K + swz;
    const unsigned short* gB = Bt + (size_t)n0 * K + swz;

    // prologue: stage tile 0 into buf 0
#pragma unroll
    for (int i = 0; i < 4; ++i) {
        gload16(gA + (size_t)(r + 32 * i) * K, &smA[0][i * 2048 + tid * 8]);
        gload16(gB + (size_t)(r + 32 * i) * K, &smB[0][i * 2048 + tid * 8]);
    }
    __syncthreads();

#pragma unroll
    for (int t = 0; t < NT; ++t) {
        const int cur = t & 1;
        if (t + 1 < NT) {  // prefetch next k-chunk into the other buffer
            const int k0 = (t + 1) * 64;
#pragma unroll
            for (int i = 0; i < 4; ++i) {
                gload16(gA + (size_t)(r + 32 * i) * K + k0, &smA[cur ^ 1][i * 2048 + tid * 8]);
                gload16(gB + (size_t)(r + 32 * i) * K + k0, &smB[cur ^ 1][i * 2048 + tid * 8]);
            }
        }
        bf16x8 af[2][4], bff[2][4];
#pragma unroll
        for (int kk = 0; kk < 2; ++kk) {
            const int ke = kk * 32 + g * 8;
#pragma unroll
            for (int m = 0; m < 4; ++m) {
                const int row = wr * 64 + m * 16 + rlo;
                af[kk][m] = *(const bf16x8*)(&smA[cur][row * 64 + (ke ^ ((row & 7) * 8))]);
            }
#pragma unroll
            for (int nn2 = 0; nn2 < 4; ++nn2) {
                const int row = wc * 64 + nn2 * 16 + rlo;
                bff[kk][nn2] = *(const bf16x8*)(&smB[cur][row * 64 + (ke ^ ((row & 7) * 8))]);
            }
        }
#pragma unroll
        for (int kk = 0; kk < 2; ++kk)
#pragma unroll
            for (int m = 0; m < 4; ++m)
#pragma unroll
                for (int nn2 = 0; nn2 < 4; ++nn2)
                    acc[m][nn2] = __builtin_amdgcn_mfma_f32_16x16x32_bf16(
                        af[kk][m], bff[kk][nn2], acc[m][nn2], 0, 0, 0);
        __syncthreads();  // drains prefetch vmem + protects buffer reuse
    }

    // epilogue via LDS (smA = 32KB = full 128x128 bf16 tile)
    unsigned short* ep = &smA[0][0];
#pragma unroll
    for (int m = 0; m < 4; ++m)
#pragma unroll
        for (int nn2 = 0; nn2 < 4; ++nn2) {
            const int col = wc * 64 + nn2 * 16 + rlo;
#pragma unroll
            for (int j = 0; j < 4; ++j) {
                const int row = wr * 64 + m * 16 + g * 4 + j;
                const int chunk = (col >> 3) ^ (row & 15);
                ep[row * 128 + chunk * 8 + (col & 7)] = f2bf(acc[m][nn2][j]);
            }
        }
    __syncthreads();
    {
        const int rr = tid >> 1;
        const int cb = (tid & 1) * 8;
#pragma unroll
        for (int k2 = 0; k2 < 8; ++k2) {
            const int c = cb + k2;
            const int pc = c ^ (rr & 15);
            const u16x8 v = *(const u16x8*)(&ep[rr * 128 + pc * 8]);
            *(u16x8*)(&C[(size_t)(m0 + rr) * NC + n0 + c * 8]) = v;
        }
    }
}

// ---- chunk-parallel SRU scan, plane-major U ----
// U row m = t*NB+b; planes for dir: col dbase + j*128 + h, dbase = dir*dbstride.
// Channel fc in [0, dirs*8192): dir = dirbase + (fc>>13), b = (fc>>7)&63, h = fc&127.
// Global channel fcg = dir*8192 + (fc & 8191).

template <int NC>
__global__ __launch_bounds__(256) void scanA(const unsigned short* __restrict__ U,
                                             const float* __restrict__ bias,
                                             float* __restrict__ aArr,
                                             float* __restrict__ bArr,
                                             int dirbase, int dbstride,
                                             int chmask, int chshift, int T) {
    const int gid = blockIdx.x * 256 + threadIdx.x;
    const int fc = gid & chmask;
    const int q = gid >> chshift;
    const int dir = dirbase + (fc >> 13);
    const int b = (fc >> 7) & 63, h = fc & 127;
    const int dbase = (fc >> 13) * dbstride;
    const float bfb = bias[dir * HID + h];

    float aa = 1.0f, cc = 0.0f;
#pragma unroll 4
    for (int i = 0; i < SUB; ++i) {
        const int s = q * SUB + i;
        const int t = dir ? (T - 1 - s) : s;
        const size_t m = (size_t)t * NB + b;
        const float u0 = bf2f(U[m * NC + dbase + h]);
        const float u1 = bf2f(U[m * NC + dbase + 128 + h]);
        const float f = sigmoidf_(u1 + bfb);
        cc = f * cc + (1.0f - f) * u0;
        aa *= f;
    }
    const int fcg = dir * 8192 + (fc & 8191);
    aArr[(size_t)q * NCH + fcg] = aa;
    bArr[(size_t)q * NCH + fcg] = cc;
}

__global__ __launch_bounds__(256) void scanB(const float* __restrict__ aArr,
                                             const float* __restrict__ bArr,
                                             float* __restrict__ cin,
                                             float* __restrict__ carry,
                                             int Q, int init, int fcg0) {
    const int fcg = fcg0 + blockIdx.x * 256 + threadIdx.x;
    float c = init ? 0.0f : carry[fcg];
    for (int q = 0; q < Q; ++q) {
        cin[(size_t)q * NCH + fcg] = c;
        c = aArr[(size_t)q * NCH + fcg] * c + bArr[(size_t)q * NCH + fcg];
    }
    carry[fcg] = c;
}

template <int NC, bool XP_FROM_U, bool ACC>
__global__ __launch_bounds__(256) void scanC(const unsigned short* __restrict__ U,
                                             const unsigned short* __restrict__ Xprev,
                                             const float* __restrict__ bias,
                                             const float* __restrict__ cin,
                                             unsigned short* __restrict__ Xout,
                                             float* __restrict__ part,
                                             int dirbase, int dbstride,
                                             int chmask, int chshift,
                                             int T, int t0, int qg0) {
    const int gid = blockIdx.x * 256 + threadIdx.x;
    const int fc = gid & chmask;
    const int q = gid >> chshift;
    const int dir = dirbase + (fc >> 13);
    const int b = (fc >> 7) & 63, h = fc & 127;
    const int dbase = (fc >> 13) * dbstride;
    const float bfb = bias[dir * HID + h];
    const float brb = bias[2 * HID + dir * HID + h];
    const int fcg = dir * 8192 + (fc & 8191);

    float c = cin[(size_t)q * NCH + fcg];
    float psum = 0.0f;
#pragma unroll 4
    for (int i = 0; i < SUB; ++i) {
        const int s = q * SUB + i;
        const int t = dir ? (T - 1 - s) : s;
        const size_t m = (size_t)t * NB + b;
        const size_t xrow = ((size_t)(t0 + t) * NB + b) * (2 * HID) + dir * HID + h;
        const float u0 = bf2f(U[m * NC + dbase + h]);
        const float u1 = bf2f(U[m * NC + dbase + 128 + h]);
        const float u2 = bf2f(U[m * NC + dbase + 256 + h]);
        float xp;
        if constexpr (XP_FROM_U) xp = bf2f(U[m * NC + dbase + 384 + h]);
        else                     xp = bf2f(Xprev[xrow]);
        const float f = sigmoidf_(u1 + bfb);
        const float r = sigmoidf_(u2 + brb);
        c = f * c + (1.0f - f) * u0;
        const float ho = r * seluf_(c) + (1.0f - r) * xp;
        if constexpr (ACC) psum += ho;
        else               Xout[xrow] = f2bf(ho);
    }
    if constexpr (ACC)
        part[(size_t)(qg0 + q) * (NB * 256) + b * 256 + dir * HID + h] = psum;
}

__global__ __launch_bounds__(256) void pool2(const float* __restrict__ part,
                                             const float* __restrict__ gamma,
                                             const float* __restrict__ beta,
                                             float* __restrict__ out) {
    const int b = blockIdx.x, chn = threadIdx.x;
    float s = 0.0f;
#pragma unroll
    for (int i = 0; i < NQG; ++i) s += part[(size_t)i * (NB * 256) + b * 256 + chn];
    const float feat = s * (1.0f / LSEQ);
    __shared__ float red[256];
    red[chn] = feat; __syncthreads();
    for (int off = 128; off > 0; off >>= 1) { if (chn < off) red[chn] += red[chn + off]; __syncthreads(); }
    const float mu = red[0] * (1.0f / 256.0f);
    __syncthreads();
    const float d = feat - mu;
    red[chn] = d * d; __syncthreads();
    for (int off = 128; off > 0; off >>= 1) { if (chn < off) red[chn] += red[chn + off]; __syncthreads(); }
    const float var = red[0] * (1.0f / 256.0f);
    out[b * 256 + chn] = d * rsqrtf(var + 1e-5f) * gamma[chn] + beta[chn];
}

extern "C" void kernel_launch(void* const* d_in, const int* in_sizes, int n_in,
                              void* d_out, int out_size, void* d_ws, size_t ws_size,
                              hipStream_t stream) {
    const float* input = (const float*)d_in[0];
    const float* gamma = (const float*)d_in[3];
    const float* beta  = (const float*)d_in[4];
    const float* Wl[4] = { (const float*)d_in[1], (const float*)d_in[5],
                           (const float*)d_in[7], (const float*)d_in[9] };
    const float* bl[4] = { (const float*)d_in[2], (const float*)d_in[6],
                           (const float*)d_in[8], (const float*)d_in[10] };
    float* out = (float*)d_out;

    char* base = (char*)d_ws;
    size_t off = 0;
    auto alloc = [&](size_t bytes) { size_t o = off; off = (off + bytes + 255) & ~(size_t)255; return o; };

    unsigned short* Wt[4];
    Wt[0] = (unsigned short*)(base + alloc((size_t)1024 * 128 * 2));
    for (int i = 1; i < 4; ++i) Wt[i] = (unsigned short*)(base + alloc((size_t)768 * 256 * 2));
    unsigned short* Xa = (unsigned short*)(base + alloc((size_t)LSEQ * NB * 256 * 2));
    unsigned short* Xb = (unsigned short*)(base + alloc((size_t)LSEQ * NB * 256 * 2));
    unsigned short* Xc = (unsigned short*)(base + alloc((size_t)LSEQ * NB * 128 * 2));
    float* carry = (float*)(base + alloc((size_t)NCH * 4));
    float* aArr  = (float*)(base + alloc((size_t)32 * NCH * 4));
    float* bArr  = (float*)(base + alloc((size_t)32 * NCH * 4));
    float* cinArr= (float*)(base + alloc((size_t)32 * NCH * 4));
    float* part  = (float*)(base + alloc((size_t)NQG * NB * 256 * 4));
    if (ws_size < off + (1u << 21)) return;
    const size_t uavail = ws_size - off;
    unsigned short* U = (unsigned short*)(base + off);

    conv_in<<<(LSEQ * NB * 128 / 4 + 255) / 256, 256, 0, stream>>>(input, Xc, LSEQ * NB * 128 / 4);
    conv_wt<<<(128 * 1024 + 255) / 256, 256, 0, stream>>>(Wl[0], Wt[0], 128, 1024, 4);
    for (int i = 1; i < 4; ++i)
        conv_wt<<<(256 * 768 + 255) / 256, 256, 0, stream>>>(Wl[i], Wt[i], 256, 768, 3);

    const unsigned short* Xin[4] = { Xc, Xa, Xb, Xa };
    unsigned short* Xout[4] = { Xa, Xb, Xa, nullptr };

    if (uavail >= (size_t)LSEQ * NB * 1024 * 2) {
        // ---- merged-dir path: T=1024, one GEMM + one scanA/B/C per layer ----
        const int T = LSEQ, Q = T / SUB;  // Q = 32
        const int nm = T * NB / 128;      // 512
        const dim3 sgrid(NCH * Q / 256);
        for (int layer = 0; layer < 4; ++layer) {
            const int kw = (layer == 0) ? 4 : 3;
            const int dbstride = 128 * kw;
            if (layer == 0)
                gemm_v3<128, 1024><<<dim3(nm * 8), 256, 0, stream>>>(Xin[0], Wt[0], U);
            else
                gemm_v3<256, 768><<<dim3(nm * 6), 256, 0, stream>>>(Xin[layer], Wt[layer], U);
            if (layer == 0)
                scanA<1024><<<sgrid, 256, 0, stream>>>(U, bl[0], aArr, bArr, 0, dbstride,
                                                       NCH - 1, 14, T);
            else
                scanA<768><<<sgrid, 256, 0, stream>>>(U, bl[layer], aArr, bArr, 0, dbstride,
                                                      NCH - 1, 14, T);
            scanB<<<NCH / 256, 256, 0, stream>>>(aArr, bArr, cinArr, carry, Q, 1, 0);
            if (layer == 0)
                scanC<1024, true, false><<<sgrid, 256, 0, stream>>>(
                    U, nullptr, bl[0], cinArr, Xout[0], nullptr, 0, dbstride, NCH - 1, 14, T, 0, 0);
            else if (layer < 3)
                scanC<768, false, false><<<sgrid, 256, 0, stream>>>(
                    U, Xin[layer], bl[layer], cinArr, Xout[layer], nullptr, 0, dbstride,
                    NCH - 1, 14, T, 0, 0);
            else
                scanC<768, false, true><<<sgrid, 256, 0, stream>>>(
                    U, Xin[3], bl[3], cinArr, nullptr, part, 0, dbstride, NCH - 1, 14, T, 0, 0);
        }
    } else {
        // ---- fallback: per-dir GEMM + scans, largest T that fits (per-dir kw=4) ----
        int T = 0;
        for (int t = 512; t >= SUB; t >>= 1)
            if ((size_t)t * NB * 512 * 2 <= uavail) { T = t; break; }
        if (T == 0) return;
        const int C = LSEQ / T, Q = T / SUB;
        const int nm = T * NB / 128;
        const dim3 sgrid(8192 * Q / 256);
        for (int layer = 0; layer < 4; ++layer) {
            const int kw = (layer == 0) ? 4 : 3;
            const int K = (layer == 0) ? 128 : 256;
            const int Nc = 128 * kw;
            for (int dir = 0; dir < 2; ++dir) {
                const unsigned short* Bts = Wt[layer] + (size_t)dir * Nc * K;
                for (int cc = 0; cc < C; ++cc) {
                    const int ci = dir ? (C - 1 - cc) : cc;
                    const unsigned short* Ap = Xin[layer] + (size_t)ci * T * NB * K;
                    if (layer == 0)
                        gemm_v3<128, 512><<<dim3(nm * 4), 256, 0, stream>>>(Ap, Bts, U);
                    else
                        gemm_v3<256, 384><<<dim3(nm * 3), 256, 0, stream>>>(Ap, Bts, U);
                    if (layer == 0)
                        scanA<512><<<sgrid, 256, 0, stream>>>(U, bl[0], aArr, bArr, dir, 0,
                                                              8191, 13, T);
                    else
                        scanA<384><<<sgrid, 256, 0, stream>>>(U, bl[layer], aArr, bArr, dir, 0,
                                                              8191, 13, T);
                    scanB<<<32, 256, 0, stream>>>(aArr, bArr, cinArr, carry, Q,
                                                  cc == 0 ? 1 : 0, dir * 8192);
                    if (layer == 0)
                        scanC<512, true, false><<<sgrid, 256, 0, stream>>>(
                            U, nullptr, bl[0], cinArr, Xout[0], nullptr, dir, 0,
                            8191, 13, T, ci * T, ci * Q);
                    else if (layer < 3)
                        scanC<384, false, false><<<sgrid, 256, 0, stream>>>(
                            U, Xin[layer], bl[layer], cinArr, Xout[layer], nullptr, dir, 0,
                            8191, 13, T, ci * T, ci * Q);
                    else
                        scanC<384, false, true><<<sgrid, 256, 0, stream>>>(
                            U, Xin[3], bl[3], cinArr, nullptr, part, dir, 0,
                            8191, 13, T, ci * T, ci * Q);
                }
            }
        }
    }
    pool2<<<NB, 256, 0, stream>>>(part, gamma, beta, out);
}

// Round 7
// 489.189 us; speedup vs baseline: 1.6595x; 1.0619x over previous
//
#include <hip/hip_runtime.h>
#include <math.h>

#define HID 128
#define LSEQ 1024
#define NB 64  // batch
#define SUB 32           // subchunk length for chunk-parallel scan
#define NQG (LSEQ / SUB) // 32 time-subchunks per direction
#define NCH 16384        // total channels (2 dirs * 64 b * 128 h)

typedef __attribute__((ext_vector_type(4))) float f32x4;
typedef __attribute__((ext_vector_type(8))) short bf16x8;
typedef __attribute__((ext_vector_type(8))) unsigned short u16x8;
typedef __attribute__((ext_vector_type(4))) unsigned short u16x4;

#define VMCNT0() asm volatile("s_waitcnt vmcnt(0)" ::: "memory")
#define VMCNT8() asm volatile("s_waitcnt vmcnt(8)" ::: "memory")
#define LGKMCNT0() asm volatile("s_waitcnt lgkmcnt(0)" ::: "memory")

__device__ __forceinline__ unsigned short f2bf(float x) {
    union { float f; unsigned int u; } a; a.f = x;
    unsigned int r = a.u + 0x7FFFu + ((a.u >> 16) & 1u);
    return (unsigned short)(r >> 16);
}
__device__ __forceinline__ float bf2f(unsigned short h) {
    union { float f; unsigned int u; } a; a.u = ((unsigned int)h) << 16;
    return a.f;
}
__device__ __forceinline__ float sigmoidf_(float x) { return 1.0f / (1.0f + __expf(-x)); }
__device__ __forceinline__ float seluf_(float x) {
    const float sc = 1.0507009873554805f, al = 1.6732632423543772f;
    return x > 0.0f ? sc * x : sc * al * (__expf(x) - 1.0f);
}

__device__ __forceinline__ void gload16(const unsigned short* g, unsigned short* l) {
    __builtin_amdgcn_global_load_lds(
        (const __attribute__((address_space(1))) unsigned int*)g,
        (__attribute__((address_space(3))) unsigned int*)l, 16, 0, 0);
}

// W (K x N fp32, N = 2*128*kw) -> Wt plane-major: row n' = dir*128*kw + j*128 + h
__global__ __launch_bounds__(256) void conv_wt(const float* __restrict__ W,
                                               unsigned short* __restrict__ Wt,
                                               int K, int N, int kw) {
    int idx = blockIdx.x * 256 + threadIdx.x;
    if (idx >= K * N) return;
    int k = idx / N, n = idx - k * N;
    const int dir = n / (128 * kw);
    const int rem = n - dir * 128 * kw;
    const int h = rem / kw, j = rem - h * kw;
    const int np = dir * 128 * kw + j * 128 + h;
    Wt[(size_t)np * K + k] = f2bf(W[idx]);
}

__global__ __launch_bounds__(256) void conv_in(const float* __restrict__ in,
                                               unsigned short* __restrict__ outp,
                                               int n4) {
    int idx = blockIdx.x * 256 + threadIdx.x;
    if (idx >= n4) return;
    const float4 v = *reinterpret_cast<const float4*>(in + (size_t)idx * 4);
    u16x4 w;
    w[0] = f2bf(v.x); w[1] = f2bf(v.y); w[2] = f2bf(v.z); w[3] = f2bf(v.w);
    *(u16x4*)(outp + (size_t)idx * 4) = w;
}

// C[M x NC] = A[M x K] * Bt[NC x K]^T, bf16/fp32-acc/bf16. 128x128 tile, BK=64,
// 4 waves. Counted-vmcnt 2-phase pipeline (T3/T4): 2 tiles in flight, never
// drain vmcnt to 0 mid-loop. XCD-friendly 1D grid: bid = mg*(NN*8) + n*8 + mi.
template <int K, int NC>
__global__ __launch_bounds__(256) void gemm_v4(const unsigned short* __restrict__ A,
                                               const unsigned short* __restrict__ Bt,
                                               unsigned short* __restrict__ C) {
    constexpr int NN = NC / 128;
    constexpr int NT = K / 64;
    __shared__ __align__(16) unsigned short smA[2][128 * 64];
    __shared__ __align__(16) unsigned short smB[2][128 * 64];

    const int bid = blockIdx.x;
    const int mi = bid & 7;
    const int tt = bid >> 3;
    const int n = tt % NN;
    const int mg = tt / NN;
    const int m0 = (mg * 8 + mi) * 128;
    const int n0 = n * 128;

    const int tid = threadIdx.x;
    const int r = tid >> 3, c8 = tid & 7;
    const int swz = (c8 * 8) ^ ((r & 7) * 8);  // involution: applied to src AND read

    const int lane = tid & 63;
    const int wid = tid >> 6;
    const int wr = wid >> 1, wc = wid & 1;
    const int rlo = lane & 15, g = lane >> 4;

    f32x4 acc[4][4] = {};

    const unsigned short* gA = A + (size_t)m0 * K + swz;
    const unsigned short* gB = Bt + (size_t)n0 * K + swz;

    // prologue: stage tiles 0 and 1 (16 loads in flight per thread)
#pragma unroll
    for (int i = 0; i < 4; ++i) {
        gload16(gA + (size_t)(r + 32 * i) * K, &smA[0][i * 2048 + tid * 8]);
        gload16(gB + (size_t)(r + 32 * i) * K, &smB[0][i * 2048 + tid * 8]);
    }
    if (NT > 1) {
#pragma unroll
        for (int i = 0; i < 4; ++i) {
            gload16(gA + (size_t)(r + 32 * i) * K + 64, &smA[1][i * 2048 + tid * 8]);
            gload16(gB + (size_t)(r + 32 * i) * K + 64, &smB[1][i * 2048 + tid * 8]);
        }
        VMCNT8();  // tile 0 landed, tile 1 still in flight
    } else {
        VMCNT0();
    }
    __builtin_amdgcn_sched_barrier(0);
    __builtin_amdgcn_s_barrier();

#pragma unroll
    for (int t = 0; t < NT; ++t) {
        const int cur = t & 1;
        bf16x8 af[2][4], bff[2][4];
#pragma unroll
        for (int kk = 0; kk < 2; ++kk) {
            const int ke = kk * 32 + g * 8;
#pragma unroll
            for (int m = 0; m < 4; ++m) {
                const int row = wr * 64 + m * 16 + rlo;
                af[kk][m] = *(const bf16x8*)(&smA[cur][row * 64 + (ke ^ ((row & 7) * 8))]);
            }
#pragma unroll
            for (int nn2 = 0; nn2 < 4; ++nn2) {
                const int row = wc * 64 + nn2 * 16 + rlo;
                bff[kk][nn2] = *(const bf16x8*)(&smB[cur][row * 64 + (ke ^ ((row & 7) * 8))]);
            }
        }
        LGKMCNT0();  // my reads of buf[cur] are in registers
        __builtin_amdgcn_sched_barrier(0);
        __builtin_amdgcn_s_barrier();  // ALL waves done reading buf[cur]
        if (t + 2 < NT) {  // refill buf[cur] with tile t+2
            const int k0 = (t + 2) * 64;
#pragma unroll
            for (int i = 0; i < 4; ++i) {
                gload16(gA + (size_t)(r + 32 * i) * K + k0, &smA[cur][i * 2048 + tid * 8]);
                gload16(gB + (size_t)(r + 32 * i) * K + k0, &smB[cur][i * 2048 + tid * 8]);
            }
        }
        __builtin_amdgcn_sched_barrier(0);  // keep MFMA after the stage-issue
#pragma unroll
        for (int kk = 0; kk < 2; ++kk)
#pragma unroll
            for (int m = 0; m < 4; ++m)
#pragma unroll
                for (int nn2 = 0; nn2 < 4; ++nn2)
                    acc[m][nn2] = __builtin_amdgcn_mfma_f32_16x16x32_bf16(
                        af[kk][m], bff[kk][nn2], acc[m][nn2], 0, 0, 0);
        if (t + 1 < NT) {  // tile t+1 must be resident before next iter reads it
            if (t + 2 < NT) { VMCNT8(); } else { VMCNT0(); }
            __builtin_amdgcn_sched_barrier(0);
            __builtin_amdgcn_s_barrier();
        }
    }
    __syncthreads();  // all waves done with LDS before epilogue overwrites it

    // epilogue via LDS (smA = 32KB = full 128x128 bf16 tile)
    unsigned short* ep = &smA[0][0];
#pragma unroll
    for (int m = 0; m < 4; ++m)
#pragma unroll
        for (int nn2 = 0; nn2 < 4; ++nn2) {
            const int col = wc * 64 + nn2 * 16 + rlo;
#pragma unroll
            for (int j = 0; j < 4; ++j) {
                const int row = wr * 64 + m * 16 + g * 4 + j;
                const int chunk = (col >> 3) ^ (row & 15);
                ep[row * 128 + chunk * 8 + (col & 7)] = f2bf(acc[m][nn2][j]);
            }
        }
    __syncthreads();
    {
        const int rr = tid >> 1;
        const int cb = (tid & 1) * 8;
#pragma unroll
        for (int k2 = 0; k2 < 8; ++k2) {
            const int c = cb + k2;
            const int pc = c ^ (rr & 15);
            const u16x8 v = *(const u16x8*)(&ep[rr * 128 + pc * 8]);
            *(u16x8*)(&C[(size_t)(m0 + rr) * NC + n0 + c * 8]) = v;
        }
    }
}

// ---- chunk-parallel SRU scan, plane-major U ----
// U row m = t*NB+b; planes for dir: col dbase + j*128 + h, dbase = dir*dbstride.
// Channel fc in [0, dirs*8192): dir = dirbase + (fc>>13), b = (fc>>7)&63, h = fc&127.

template <int NC>
__global__ __launch_bounds__(256) void scanA(const unsigned short* __restrict__ U,
                                             const float* __restrict__ bias,
                                             float* __restrict__ aArr,
                                             float* __restrict__ bArr,
                                             int dirbase, int dbstride,
                                             int chmask, int chshift, int T) {
    const int gid = blockIdx.x * 256 + threadIdx.x;
    const int fc = gid & chmask;
    const int q = gid >> chshift;
    const int dir = dirbase + (fc >> 13);
    const int b = (fc >> 7) & 63, h = fc & 127;
    const int dbase = (fc >> 13) * dbstride;
    const float bfb = bias[dir * HID + h];

    float aa = 1.0f, cc = 0.0f;
#pragma unroll 4
    for (int i = 0; i < SUB; ++i) {
        const int s = q * SUB + i;
        const int t = dir ? (T - 1 - s) : s;
        const size_t m = (size_t)t * NB + b;
        const float u0 = bf2f(U[m * NC + dbase + h]);
        const float u1 = bf2f(U[m * NC + dbase + 128 + h]);
        const float f = sigmoidf_(u1 + bfb);
        cc = f * cc + (1.0f - f) * u0;
        aa *= f;
    }
    const int fcg = dir * 8192 + (fc & 8191);
    aArr[(size_t)q * NCH + fcg] = aa;
    bArr[(size_t)q * NCH + fcg] = cc;
}

// Phase B: register-resident, fully unrolled (Q compile-time) — loads issued
// up front, one latency instead of Q dependent ones.
template <int Q>
__global__ __launch_bounds__(256) void scanB(const float* __restrict__ aArr,
                                             const float* __restrict__ bArr,
                                             float* __restrict__ cin,
                                             float* __restrict__ carry,
                                             int init, int fcg0) {
    const int fcg = fcg0 + blockIdx.x * 256 + threadIdx.x;
    float a[Q], bb[Q];
#pragma unroll
    for (int q = 0; q < Q; ++q) {
        a[q]  = aArr[(size_t)q * NCH + fcg];
        bb[q] = bArr[(size_t)q * NCH + fcg];
    }
    float c = init ? 0.0f : carry[fcg];
#pragma unroll
    for (int q = 0; q < Q; ++q) {
        cin[(size_t)q * NCH + fcg] = c;
        c = a[q] * c + bb[q];
    }
    carry[fcg] = c;
}

template <int NC, bool XP_FROM_U, bool ACC>
__global__ __launch_bounds__(256) void scanC(const unsigned short* __restrict__ U,
                                             const unsigned short* __restrict__ Xprev,
                                             const float* __restrict__ bias,
                                             const float* __restrict__ cin,
                                             unsigned short* __restrict__ Xout,
                                             float* __restrict__ part,
                                             int dirbase, int dbstride,
                                             int chmask, int chshift,
                                             int T, int t0, int qg0) {
    const int gid = blockIdx.x * 256 + threadIdx.x;
    const int fc = gid & chmask;
    const int q = gid >> chshift;
    const int dir = dirbase + (fc >> 13);
    const int b = (fc >> 7) & 63, h = fc & 127;
    const int dbase = (fc >> 13) * dbstride;
    const float bfb = bias[dir * HID + h];
    const float brb = bias[2 * HID + dir * HID + h];
    const int fcg = dir * 8192 + (fc & 8191);

    float c = cin[(size_t)q * NCH + fcg];
    float psum = 0.0f;
#pragma unroll 4
    for (int i = 0; i < SUB; ++i) {
        const int s = q * SUB + i;
        const int t = dir ? (T - 1 - s) : s;
        const size_t m = (size_t)t * NB + b;
        const size_t xrow = ((size_t)(t0 + t) * NB + b) * (2 * HID) + dir * HID + h;
        const float u0 = bf2f(U[m * NC + dbase + h]);
        const float u1 = bf2f(U[m * NC + dbase + 128 + h]);
        const float u2 = bf2f(U[m * NC + dbase + 256 + h]);
        float xp;
        if constexpr (XP_FROM_U) xp = bf2f(U[m * NC + dbase + 384 + h]);
        else                     xp = bf2f(Xprev[xrow]);
        const float f = sigmoidf_(u1 + bfb);
        const float r = sigmoidf_(u2 + brb);
        c = f * c + (1.0f - f) * u0;
        const float ho = r * seluf_(c) + (1.0f - r) * xp;
        if constexpr (ACC) psum += ho;
        else               Xout[xrow] = f2bf(ho);
    }
    if constexpr (ACC)
        part[(size_t)(qg0 + q) * (NB * 256) + b * 256 + dir * HID + h] = psum;
}

__global__ __launch_bounds__(256) void pool2(const float* __restrict__ part,
                                             const float* __restrict__ gamma,
                                             const float* __restrict__ beta,
                                             float* __restrict__ out) {
    const int b = blockIdx.x, chn = threadIdx.x;
    float s = 0.0f;
#pragma unroll
    for (int i = 0; i < NQG; ++i) s += part[(size_t)i * (NB * 256) + b * 256 + chn];
    const float feat = s * (1.0f / LSEQ);
    __shared__ float red[256];
    red[chn] = feat; __syncthreads();
    for (int off = 128; off > 0; off >>= 1) { if (chn < off) red[chn] += red[chn + off]; __syncthreads(); }
    const float mu = red[0] * (1.0f / 256.0f);
    __syncthreads();
    const float d = feat - mu;
    red[chn] = d * d; __syncthreads();
    for (int off = 128; off > 0; off >>= 1) { if (chn < off) red[chn] += red[chn + off]; __syncthreads(); }
    const float var = red[0] * (1.0f / 256.0f);
    out[b * 256 + chn] = d * rsqrtf(var + 1e-5f) * gamma[chn] + beta[chn];
}

extern "C" void kernel_launch(void* const* d_in, const int* in_sizes, int n_in,
                              void* d_out, int out_size, void* d_ws, size_t ws_size,
                              hipStream_t stream) {
    const float* input = (const float*)d_in[0];
    const float* gamma = (const float*)d_in[3];
    const float* beta  = (const float*)d_in[4];
    const float* Wl[4] = { (const float*)d_in[1], (const float*)d_in[5],
                           (const float*)d_in[7], (const float*)d_in[9] };
    const float* bl[4] = { (const float*)d_in[2], (const float*)d_in[6],
                           (const float*)d_in[8], (const float*)d_in[10] };
    float* out = (float*)d_out;

    char* base = (char*)d_ws;
    size_t off = 0;
    auto alloc = [&](size_t bytes) { size_t o = off; off = (off + bytes + 255) & ~(size_t)255; return o; };

    unsigned short* Wt[4];
    Wt[0] = (unsigned short*)(base + alloc((size_t)1024 * 128 * 2));
    for (int i = 1; i < 4; ++i) Wt[i] = (unsigned short*)(base + alloc((size_t)768 * 256 * 2));
    unsigned short* Xa = (unsigned short*)(base + alloc((size_t)LSEQ * NB * 256 * 2));
    unsigned short* Xb = (unsigned short*)(base + alloc((size_t)LSEQ * NB * 256 * 2));
    unsigned short* Xc = (unsigned short*)(base + alloc((size_t)LSEQ * NB * 128 * 2));
    float* carry = (float*)(base + alloc((size_t)NCH * 4));
    float* aArr  = (float*)(base + alloc((size_t)32 * NCH * 4));
    float* bArr  = (float*)(base + alloc((size_t)32 * NCH * 4));
    float* cinArr= (float*)(base + alloc((size_t)32 * NCH * 4));
    float* part  = (float*)(base + alloc((size_t)NQG * NB * 256 * 4));
    if (ws_size < off + (1u << 21)) return;
    const size_t uavail = ws_size - off;
    unsigned short* U = (unsigned short*)(base + off);

    conv_in<<<(LSEQ * NB * 128 / 4 + 255) / 256, 256, 0, stream>>>(input, Xc, LSEQ * NB * 128 / 4);
    conv_wt<<<(128 * 1024 + 255) / 256, 256, 0, stream>>>(Wl[0], Wt[0], 128, 1024, 4);
    for (int i = 1; i < 4; ++i)
        conv_wt<<<(256 * 768 + 255) / 256, 256, 0, stream>>>(Wl[i], Wt[i], 256, 768, 3);

    const unsigned short* Xin[4] = { Xc, Xa, Xb, Xa };
    unsigned short* Xout[4] = { Xa, Xb, Xa, nullptr };

    if (uavail >= (size_t)LSEQ * NB * 1024 * 2) {
        // ---- merged-dir path: T=1024, one GEMM + one scanA/B/C per layer ----
        const int T = LSEQ, Q = T / SUB;  // Q = 32
        const int nm = T * NB / 128;      // 512
        const dim3 sgrid(NCH * Q / 256);
        for (int layer = 0; layer < 4; ++layer) {
            const int kw = (layer == 0) ? 4 : 3;
            const int dbstride = 128 * kw;
            if (layer == 0)
                gemm_v4<128, 1024><<<dim3(nm * 8), 256, 0, stream>>>(Xin[0], Wt[0], U);
            else
                gemm_v4<256, 768><<<dim3(nm * 6), 256, 0, stream>>>(Xin[layer], Wt[layer], U);
            if (layer == 0)
                scanA<1024><<<sgrid, 256, 0, stream>>>(U, bl[0], aArr, bArr, 0, dbstride,
                                                       NCH - 1, 14, T);
            else
                scanA<768><<<sgrid, 256, 0, stream>>>(U, bl[layer], aArr, bArr, 0, dbstride,
                                                      NCH - 1, 14, T);
            scanB<32><<<NCH / 256, 256, 0, stream>>>(aArr, bArr, cinArr, carry, 1, 0);
            if (layer == 0)
                scanC<1024, true, false><<<sgrid, 256, 0, stream>>>(
                    U, nullptr, bl[0], cinArr, Xout[0], nullptr, 0, dbstride, NCH - 1, 14, T, 0, 0);
            else if (layer < 3)
                scanC<768, false, false><<<sgrid, 256, 0, stream>>>(
                    U, Xin[layer], bl[layer], cinArr, Xout[layer], nullptr, 0, dbstride,
                    NCH - 1, 14, T, 0, 0);
            else
                scanC<768, false, true><<<sgrid, 256, 0, stream>>>(
                    U, Xin[3], bl[3], cinArr, nullptr, part, 0, dbstride, NCH - 1, 14, T, 0, 0);
        }
    } else {
        // ---- fallback: per-dir GEMM + scans, largest T that fits (per-dir kw=4) ----
        int T = 0;
        for (int t = 512; t >= SUB; t >>= 1)
            if ((size_t)t * NB * 512 * 2 <= uavail) { T = t; break; }
        if (T == 0) return;
        const int C = LSEQ / T, Q = T / SUB;
        const int nm = T * NB / 128;
        const dim3 sgrid(8192 * Q / 256);
        for (int layer = 0; layer < 4; ++layer) {
            const int kw = (layer == 0) ? 4 : 3;
            const int K = (layer == 0) ? 128 : 256;
            const int Nc = 128 * kw;
            for (int dir = 0; dir < 2; ++dir) {
                const unsigned short* Bts = Wt[layer] + (size_t)dir * Nc * K;
                for (int cc = 0; cc < C; ++cc) {
                    const int ci = dir ? (C - 1 - cc) : cc;
                    const unsigned short* Ap = Xin[layer] + (size_t)ci * T * NB * K;
                    if (layer == 0)
                        gemm_v4<128, 512><<<dim3(nm * 4), 256, 0, stream>>>(Ap, Bts, U);
                    else
                        gemm_v4<256, 384><<<dim3(nm * 3), 256, 0, stream>>>(Ap, Bts, U);
                    if (layer == 0)
                        scanA<512><<<sgrid, 256, 0, stream>>>(U, bl[0], aArr, bArr, dir, 0,
                                                              8191, 13, T);
                    else
                        scanA<384><<<sgrid, 256, 0, stream>>>(U, bl[layer], aArr, bArr, dir, 0,
                                                              8191, 13, T);
                    if (Q == 16)
                        scanB<16><<<32, 256, 0, stream>>>(aArr, bArr, cinArr, carry,
                                                          cc == 0 ? 1 : 0, dir * 8192);
                    else
                        scanB<32><<<32, 256, 0, stream>>>(aArr, bArr, cinArr, carry,
                                                          cc == 0 ? 1 : 0, dir * 8192);
                    if (layer == 0)
                        scanC<512, true, false><<<sgrid, 256, 0, stream>>>(
                            U, nullptr, bl[0], cinArr, Xout[0], nullptr, dir, 0,
                            8191, 13, T, ci * T, ci * Q);
                    else if (layer < 3)
                        scanC<384, false, false><<<sgrid, 256, 0, stream>>>(
                            U, Xin[layer], bl[layer], cinArr, Xout[layer], nullptr, dir, 0,
                            8191, 13, T, ci * T, ci * Q);
                    else
                        scanC<384, false, true><<<sgrid, 256, 0, stream>>>(
                            U, Xin[3], bl[3], cinArr, nullptr, part, dir, 0,
                            8191, 13, T, ci * T, ci * Q);
                }
            }
        }
    }
    pool2<<<NB, 256, 0, stream>>>(part, gamma, beta, out);
}

// Round 8
// 404.327 us; speedup vs baseline: 2.0078x; 1.2099x over previous
//
#include <hip/hip_runtime.h>
#include <math.h>

#define HID 128
#define LSEQ 1024
#define NB 64  // batch
#define SUB 32           // subchunk length for chunk-parallel scan
#define NQG (LSEQ / SUB) // 32 time-subchunks per direction
#define NCH 16384        // total channels (2 dirs * 64 b * 128 h)

typedef __attribute__((ext_vector_type(4))) float f32x4;
typedef __attribute__((ext_vector_type(8))) short bf16x8;
typedef __attribute__((ext_vector_type(8))) unsigned short u16x8;
typedef __attribute__((ext_vector_type(4))) unsigned short u16x4;

template <int N>
__device__ __forceinline__ void vmcntN() {
    asm volatile("s_waitcnt vmcnt(%0)" :: "n"(N) : "memory");
}

__device__ __forceinline__ unsigned short f2bf(float x) {
    union { float f; unsigned int u; } a; a.f = x;
    unsigned int r = a.u + 0x7FFFu + ((a.u >> 16) & 1u);
    return (unsigned short)(r >> 16);
}
__device__ __forceinline__ float bf2f(unsigned short h) {
    union { float f; unsigned int u; } a; a.u = ((unsigned int)h) << 16;
    return a.f;
}
__device__ __forceinline__ float sigmoidf_(float x) { return 1.0f / (1.0f + __expf(-x)); }
__device__ __forceinline__ float seluf_(float x) {
    const float sc = 1.0507009873554805f, al = 1.6732632423543772f;
    return x > 0.0f ? sc * x : sc * al * (__expf(x) - 1.0f);
}

__device__ __forceinline__ void gload16(const unsigned short* g, unsigned short* l) {
    __builtin_amdgcn_global_load_lds(
        (const __attribute__((address_space(1))) unsigned int*)g,
        (__attribute__((address_space(3))) unsigned int*)l, 16, 0, 0);
}

// W (K x N fp32, N = 2*128*kw) -> Wt plane-major: row n' = dir*128*kw + j*128 + h
__global__ __launch_bounds__(256) void conv_wt(const float* __restrict__ W,
                                               unsigned short* __restrict__ Wt,
                                               int K, int N, int kw) {
    int idx = blockIdx.x * 256 + threadIdx.x;
    if (idx >= K * N) return;
    int k = idx / N, n = idx - k * N;
    const int dir = n / (128 * kw);
    const int rem = n - dir * 128 * kw;
    const int h = rem / kw, j = rem - h * kw;
    const int np = dir * 128 * kw + j * 128 + h;
    Wt[(size_t)np * K + k] = f2bf(W[idx]);
}

__global__ __launch_bounds__(256) void conv_in(const float* __restrict__ in,
                                               unsigned short* __restrict__ outp,
                                               int n4) {
    int idx = blockIdx.x * 256 + threadIdx.x;
    if (idx >= n4) return;
    const float4 v = *reinterpret_cast<const float4*>(in + (size_t)idx * 4);
    u16x4 w;
    w[0] = f2bf(v.x); w[1] = f2bf(v.y); w[2] = f2bf(v.z); w[3] = f2bf(v.w);
    *(u16x4*)(outp + (size_t)idx * 4) = w;
}

// Streaming GEMM for tall-skinny shape: C[M x NC] = A[M x K] * Bt[NC x K]^T.
// Block owns one 128-col n-tile with B RESIDENT in LDS (loaded once), and
// processes 4 m-tiles of 128 rows. 4 waves, each owns a private 32-row slice
// and a private 4-slot LDS ring for A staging -> ZERO barriers in main loop,
// per-wave counted vmcnt (depth-3 in flight). Swapped-operand MFMA gives
// j = 4 consecutive output columns per lane -> direct 8B packed stores.
template <int K, int NC>
__global__ __launch_bounds__(256) void gemm_v5(const unsigned short* __restrict__ A,
                                               const unsigned short* __restrict__ Bt,
                                               unsigned short* __restrict__ C) {
    constexpr int NN = NC / 128;
    constexpr int NT = K / 64;
    constexpr int NSTEP = 4 * NT;  // 4 m-tiles per block
    __shared__ __align__(16) unsigned short smB[NT * 128 * 64];
    __shared__ __align__(16) unsigned short smA[4][4][2048];  // [wave][slot]

    const int bid = blockIdx.x;
    const int mi = bid & 7;
    const int tt = bid >> 3;
    const int n = tt % NN;
    const int mg = (tt / NN) * 8 + mi;
    const int mb = mg * 512;
    const int n0 = n * 128;

    const int tid = threadIdx.x;
    const int w = tid >> 6, l = tid & 63;
    const int rlo = l & 15, g = l >> 4;
    const int kx = (l & 7) ^ (l >> 3);      // source-side swizzle for A stage
    const int kswz = (rlo & 7) * 8;         // read-side swizzle (shorts)

    // ---- B resident load (once) ----
#pragma unroll
    for (int kt = 0; kt < NT; ++kt)
#pragma unroll
        for (int rd = 0; rd < 4; ++rd) {
            const int col = rd * 32 + (tid >> 3);
            const int kxb = (tid & 7) ^ ((tid >> 3) & 7);
            gload16(Bt + (size_t)(n0 + col) * K + kt * 64 + kxb * 8,
                    &smB[kt * 8192 + rd * 2048 + tid * 8]);
        }

    auto stageA = [&](int s2) {
        const int mt2 = s2 / NT, kt2 = s2 % NT, sl = s2 & 3;
        const int rowb = mb + mt2 * 128 + w * 32;
#pragma unroll
        for (int i = 0; i < 4; ++i)
            gload16(A + (size_t)(rowb + i * 8 + (l >> 3)) * K + kt2 * 64 + kx * 8,
                    &smA[w][sl][i * 512 + l * 8]);
    };

    // prologue: 3 A-stages in flight
    stageA(0); stageA(1); stageA(2);
    vmcntN<8>();  // my B loads + stage0 landed (stages 1,2 = 8 loads outstanding)
    __builtin_amdgcn_sched_barrier(0);
    __builtin_amdgcn_s_barrier();  // all threads' B resident
    __builtin_amdgcn_sched_barrier(0);

    f32x4 acc[2][8];
#pragma unroll
    for (int s = 0; s < NSTEP; ++s) {
        const int mt = s / NT, kt = s % NT, slot = s & 3;
        if (kt == 0) {
#pragma unroll
            for (int mf = 0; mf < 2; ++mf)
#pragma unroll
                for (int nf = 0; nf < 8; ++nf) acc[mf][nf] = (f32x4){0.f, 0.f, 0.f, 0.f};
        }
        if (s + 3 < NSTEP) { stageA(s + 3); vmcntN<12>(); }
        else if (s + 3 == NSTEP) vmcntN<8>();
        else if (s + 2 == NSTEP) vmcntN<4>();
        else                     vmcntN<0>();
        __builtin_amdgcn_sched_barrier(0);

#pragma unroll
        for (int kk = 0; kk < 2; ++kk) {
            const int koff = (kk * 32 + g * 8) ^ kswz;
            bf16x8 af[2], bff[8];
#pragma unroll
            for (int mf = 0; mf < 2; ++mf)
                af[mf] = *(const bf16x8*)(&smA[w][slot][(mf * 16 + rlo) * 64 + koff]);
#pragma unroll
            for (int nf = 0; nf < 8; ++nf)
                bff[nf] = *(const bf16x8*)(&smB[kt * 8192 + (nf * 16 + rlo) * 64 + koff]);
#pragma unroll
            for (int mf = 0; mf < 2; ++mf)
#pragma unroll
                for (int nf = 0; nf < 8; ++nf)
                    acc[mf][nf] = __builtin_amdgcn_mfma_f32_16x16x32_bf16(
                        bff[nf], af[mf], acc[mf][nf], 0, 0, 0);  // swapped operands
        }

        if (kt == NT - 1) {  // epilogue: lane holds (row=...+rlo, cols g*4+j) -> 8B stores
            const int rowb = mb + mt * 128 + w * 32;
#pragma unroll
            for (int mf = 0; mf < 2; ++mf) {
                const size_t rbase = (size_t)(rowb + mf * 16 + rlo) * NC + n0 + g * 4;
#pragma unroll
                for (int nf = 0; nf < 8; ++nf) {
                    u16x4 v;
                    v[0] = f2bf(acc[mf][nf][0]); v[1] = f2bf(acc[mf][nf][1]);
                    v[2] = f2bf(acc[mf][nf][2]); v[3] = f2bf(acc[mf][nf][3]);
                    *(u16x4*)(&C[rbase + nf * 16]) = v;
                }
            }
        }
    }
}

// ---- chunk-parallel SRU scan, plane-major U ----
template <int NC>
__global__ __launch_bounds__(256) void scanA(const unsigned short* __restrict__ U,
                                             const float* __restrict__ bias,
                                             float* __restrict__ aArr,
                                             float* __restrict__ bArr,
                                             int dirbase, int dbstride,
                                             int chmask, int chshift, int T) {
    const int gid = blockIdx.x * 256 + threadIdx.x;
    const int fc = gid & chmask;
    const int q = gid >> chshift;
    const int dir = dirbase + (fc >> 13);
    const int b = (fc >> 7) & 63, h = fc & 127;
    const int dbase = (fc >> 13) * dbstride;
    const float bfb = bias[dir * HID + h];

    float aa = 1.0f, cc = 0.0f;
#pragma unroll 4
    for (int i = 0; i < SUB; ++i) {
        const int s = q * SUB + i;
        const int t = dir ? (T - 1 - s) : s;
        const size_t m = (size_t)t * NB + b;
        const float u0 = bf2f(U[m * NC + dbase + h]);
        const float u1 = bf2f(U[m * NC + dbase + 128 + h]);
        const float f = sigmoidf_(u1 + bfb);
        cc = f * cc + (1.0f - f) * u0;
        aa *= f;
    }
    const int fcg = dir * 8192 + (fc & 8191);
    aArr[(size_t)q * NCH + fcg] = aa;
    bArr[(size_t)q * NCH + fcg] = cc;
}

template <int Q>
__global__ __launch_bounds__(256) void scanB(const float* __restrict__ aArr,
                                             const float* __restrict__ bArr,
                                             float* __restrict__ cin,
                                             float* __restrict__ carry,
                                             int init, int fcg0) {
    const int fcg = fcg0 + blockIdx.x * 256 + threadIdx.x;
    float a[Q], bb[Q];
#pragma unroll
    for (int q = 0; q < Q; ++q) {
        a[q]  = aArr[(size_t)q * NCH + fcg];
        bb[q] = bArr[(size_t)q * NCH + fcg];
    }
    float c = init ? 0.0f : carry[fcg];
#pragma unroll
    for (int q = 0; q < Q; ++q) {
        cin[(size_t)q * NCH + fcg] = c;
        c = a[q] * c + bb[q];
    }
    carry[fcg] = c;
}

template <int NC, bool XP_FROM_U, bool ACC>
__global__ __launch_bounds__(256) void scanC(const unsigned short* __restrict__ U,
                                             const unsigned short* __restrict__ Xprev,
                                             const float* __restrict__ bias,
                                             const float* __restrict__ cin,
                                             unsigned short* __restrict__ Xout,
                                             float* __restrict__ part,
                                             int dirbase, int dbstride,
                                             int chmask, int chshift,
                                             int T, int t0, int qg0) {
    const int gid = blockIdx.x * 256 + threadIdx.x;
    const int fc = gid & chmask;
    const int q = gid >> chshift;
    const int dir = dirbase + (fc >> 13);
    const int b = (fc >> 7) & 63, h = fc & 127;
    const int dbase = (fc >> 13) * dbstride;
    const float bfb = bias[dir * HID + h];
    const float brb = bias[2 * HID + dir * HID + h];
    const int fcg = dir * 8192 + (fc & 8191);

    float c = cin[(size_t)q * NCH + fcg];
    float psum = 0.0f;
#pragma unroll 4
    for (int i = 0; i < SUB; ++i) {
        const int s = q * SUB + i;
        const int t = dir ? (T - 1 - s) : s;
        const size_t m = (size_t)t * NB + b;
        const size_t xrow = ((size_t)(t0 + t) * NB + b) * (2 * HID) + dir * HID + h;
        const float u0 = bf2f(U[m * NC + dbase + h]);
        const float u1 = bf2f(U[m * NC + dbase + 128 + h]);
        const float u2 = bf2f(U[m * NC + dbase + 256 + h]);
        float xp;
        if constexpr (XP_FROM_U) xp = bf2f(U[m * NC + dbase + 384 + h]);
        else                     xp = bf2f(Xprev[xrow]);
        const float f = sigmoidf_(u1 + bfb);
        const float r = sigmoidf_(u2 + brb);
        c = f * c + (1.0f - f) * u0;
        const float ho = r * seluf_(c) + (1.0f - r) * xp;
        if constexpr (ACC) psum += ho;
        else               Xout[xrow] = f2bf(ho);
    }
    if constexpr (ACC)
        part[(size_t)(qg0 + q) * (NB * 256) + b * 256 + dir * HID + h] = psum;
}

__global__ __launch_bounds__(256) void pool2(const float* __restrict__ part,
                                             const float* __restrict__ gamma,
                                             const float* __restrict__ beta,
                                             float* __restrict__ out) {
    const int b = blockIdx.x, chn = threadIdx.x;
    float s = 0.0f;
#pragma unroll
    for (int i = 0; i < NQG; ++i) s += part[(size_t)i * (NB * 256) + b * 256 + chn];
    const float feat = s * (1.0f / LSEQ);
    __shared__ float red[256];
    red[chn] = feat; __syncthreads();
    for (int off = 128; off > 0; off >>= 1) { if (chn < off) red[chn] += red[chn + off]; __syncthreads(); }
    const float mu = red[0] * (1.0f / 256.0f);
    __syncthreads();
    const float d = feat - mu;
    red[chn] = d * d; __syncthreads();
    for (int off = 128; off > 0; off >>= 1) { if (chn < off) red[chn] += red[chn + off]; __syncthreads(); }
    const float var = red[0] * (1.0f / 256.0f);
    out[b * 256 + chn] = d * rsqrtf(var + 1e-5f) * gamma[chn] + beta[chn];
}

extern "C" void kernel_launch(void* const* d_in, const int* in_sizes, int n_in,
                              void* d_out, int out_size, void* d_ws, size_t ws_size,
                              hipStream_t stream) {
    const float* input = (const float*)d_in[0];
    const float* gamma = (const float*)d_in[3];
    const float* beta  = (const float*)d_in[4];
    const float* Wl[4] = { (const float*)d_in[1], (const float*)d_in[5],
                           (const float*)d_in[7], (const float*)d_in[9] };
    const float* bl[4] = { (const float*)d_in[2], (const float*)d_in[6],
                           (const float*)d_in[8], (const float*)d_in[10] };
    float* out = (float*)d_out;

    char* base = (char*)d_ws;
    size_t off = 0;
    auto alloc = [&](size_t bytes) { size_t o = off; off = (off + bytes + 255) & ~(size_t)255; return o; };

    unsigned short* Wt[4];
    Wt[0] = (unsigned short*)(base + alloc((size_t)1024 * 128 * 2));
    for (int i = 1; i < 4; ++i) Wt[i] = (unsigned short*)(base + alloc((size_t)768 * 256 * 2));
    unsigned short* Xa = (unsigned short*)(base + alloc((size_t)LSEQ * NB * 256 * 2));
    unsigned short* Xb = (unsigned short*)(base + alloc((size_t)LSEQ * NB * 256 * 2));
    unsigned short* Xc = (unsigned short*)(base + alloc((size_t)LSEQ * NB * 128 * 2));
    float* carry = (float*)(base + alloc((size_t)NCH * 4));
    float* aArr  = (float*)(base + alloc((size_t)32 * NCH * 4));
    float* bArr  = (float*)(base + alloc((size_t)32 * NCH * 4));
    float* cinArr= (float*)(base + alloc((size_t)32 * NCH * 4));
    float* part  = (float*)(base + alloc((size_t)NQG * NB * 256 * 4));
    if (ws_size < off + (1u << 21)) return;
    const size_t uavail = ws_size - off;
    unsigned short* U = (unsigned short*)(base + off);

    conv_in<<<(LSEQ * NB * 128 / 4 + 255) / 256, 256, 0, stream>>>(input, Xc, LSEQ * NB * 128 / 4);
    conv_wt<<<(128 * 1024 + 255) / 256, 256, 0, stream>>>(Wl[0], Wt[0], 128, 1024, 4);
    for (int i = 1; i < 4; ++i)
        conv_wt<<<(256 * 768 + 255) / 256, 256, 0, stream>>>(Wl[i], Wt[i], 256, 768, 3);

    const unsigned short* Xin[4] = { Xc, Xa, Xb, Xa };
    unsigned short* Xout[4] = { Xa, Xb, Xa, nullptr };

    if (uavail >= (size_t)LSEQ * NB * 1024 * 2) {
        // ---- merged-dir path: T=1024, one GEMM + one scanA/B/C per layer ----
        const int T = LSEQ, Q = T / SUB;  // Q = 32
        const dim3 sgrid(NCH * Q / 256);
        for (int layer = 0; layer < 4; ++layer) {
            const int kw = (layer == 0) ? 4 : 3;
            const int dbstride = 128 * kw;
            if (layer == 0)
                gemm_v5<128, 1024><<<dim3(8 * 128), 256, 0, stream>>>(Xin[0], Wt[0], U);
            else
                gemm_v5<256, 768><<<dim3(6 * 128), 256, 0, stream>>>(Xin[layer], Wt[layer], U);
            if (layer == 0)
                scanA<1024><<<sgrid, 256, 0, stream>>>(U, bl[0], aArr, bArr, 0, dbstride,
                                                       NCH - 1, 14, T);
            else
                scanA<768><<<sgrid, 256, 0, stream>>>(U, bl[layer], aArr, bArr, 0, dbstride,
                                                      NCH - 1, 14, T);
            scanB<32><<<NCH / 256, 256, 0, stream>>>(aArr, bArr, cinArr, carry, 1, 0);
            if (layer == 0)
                scanC<1024, true, false><<<sgrid, 256, 0, stream>>>(
                    U, nullptr, bl[0], cinArr, Xout[0], nullptr, 0, dbstride, NCH - 1, 14, T, 0, 0);
            else if (layer < 3)
                scanC<768, false, false><<<sgrid, 256, 0, stream>>>(
                    U, Xin[layer], bl[layer], cinArr, Xout[layer], nullptr, 0, dbstride,
                    NCH - 1, 14, T, 0, 0);
            else
                scanC<768, false, true><<<sgrid, 256, 0, stream>>>(
                    U, Xin[3], bl[3], cinArr, nullptr, part, 0, dbstride, NCH - 1, 14, T, 0, 0);
        }
    } else {
        // ---- fallback: per-dir GEMM + scans, largest T that fits (per-dir kw=4) ----
        int T = 0;
        for (int t = 512; t >= 64; t >>= 1)
            if ((size_t)t * NB * 512 * 2 <= uavail) { T = t; break; }
        if (T == 0) return;
        const int C = LSEQ / T, Q = T / SUB;
        const int nmg = T * NB / 512;
        const dim3 sgrid(8192 * Q / 256);
        for (int layer = 0; layer < 4; ++layer) {
            const int kw = (layer == 0) ? 4 : 3;
            const int K = (layer == 0) ? 128 : 256;
            const int Nc = 128 * kw;
            for (int dir = 0; dir < 2; ++dir) {
                const unsigned short* Bts = Wt[layer] + (size_t)dir * Nc * K;
                for (int cc = 0; cc < C; ++cc) {
                    const int ci = dir ? (C - 1 - cc) : cc;
                    const unsigned short* Ap = Xin[layer] + (size_t)ci * T * NB * K;
                    if (layer == 0)
                        gemm_v5<128, 512><<<dim3(4 * nmg), 256, 0, stream>>>(Ap, Bts, U);
                    else
                        gemm_v5<256, 384><<<dim3(3 * nmg), 256, 0, stream>>>(Ap, Bts, U);
                    if (layer == 0)
                        scanA<512><<<sgrid, 256, 0, stream>>>(U, bl[0], aArr, bArr, dir, 0,
                                                              8191, 13, T);
                    else
                        scanA<384><<<sgrid, 256, 0, stream>>>(U, bl[layer], aArr, bArr, dir, 0,
                                                              8191, 13, T);
                    if (Q == 16)
                        scanB<16><<<32, 256, 0, stream>>>(aArr, bArr, cinArr, carry,
                                                          cc == 0 ? 1 : 0, dir * 8192);
                    else
                        scanB<32><<<32, 256, 0, stream>>>(aArr, bArr, cinArr, carry,
                                                          cc == 0 ? 1 : 0, dir * 8192);
                    if (layer == 0)
                        scanC<512, true, false><<<sgrid, 256, 0, stream>>>(
                            U, nullptr, bl[0], cinArr, Xout[0], nullptr, dir, 0,
                            8191, 13, T, ci * T, ci * Q);
                    else if (layer < 3)
                        scanC<384, false, false><<<sgrid, 256, 0, stream>>>(
                            U, Xin[layer], bl[layer], cinArr, Xout[layer], nullptr, dir, 0,
                            8191, 13, T, ci * T, ci * Q);
                    else
                        scanC<384, false, true><<<sgrid, 256, 0, stream>>>(
                            U, Xin[3], bl[3], cinArr, nullptr, part, dir, 0,
                            8191, 13, T, ci * T, ci * Q);
                }
            }
        }
    }
    pool2<<<NB, 256, 0, stream>>>(part, gamma, beta, out);
}